// Round 9
// baseline (30.877 us; speedup 1.0000x reference)
//
#include <hip/hip_runtime.h>
#include <hip/hip_bf16.h>

#define TOKS 2048
#define FEAT 2048
#define NR   128
#define KB   32
#define NCB  128            // column blocks in x
#define CBW  (TOKS * 32)    // bytes per colblock slab in xb: 2048 tok * 32 B

typedef __attribute__((ext_vector_type(8))) short bf16x8;
typedef __attribute__((ext_vector_type(4))) float f32x4;

__device__ __forceinline__ unsigned short f2bf(float f) {
    unsigned u = __builtin_bit_cast(unsigned, f);
    u += 0x7FFFu + ((u >> 16) & 1u);
    return (unsigned short)(u >> 16);
}

__device__ __forceinline__ bf16x8 pack8(float4 a, float4 b) {
    bf16x8 r;
    r[0] = (short)f2bf(a.x); r[1] = (short)f2bf(a.y);
    r[2] = (short)f2bf(a.z); r[3] = (short)f2bf(a.w);
    r[4] = (short)f2bf(b.x); r[5] = (short)f2bf(b.y);
    r[6] = (short)f2bf(b.z); r[7] = (short)f2bf(b.w);
    return r;
}

// Prep: bid<1024 -> x f32[2048][2048] -> xb bf16[128 cb][2048 tok][16]
//       bid>=1024 -> values f32 -> vb bf16 (linear)
__global__ __launch_bounds__(256) void prep9(const float* __restrict__ x,
                                             const float* __restrict__ v,
                                             unsigned short* __restrict__ xb,
                                             unsigned short* __restrict__ vb) {
    int bid = blockIdx.x, tid = threadIdx.x;
    if (bid < 1024) {
        int cbi = tid & 127, tp = tid >> 7;
        int tok = bid * 2 + tp;
        const float4* p = reinterpret_cast<const float4*>(x + (size_t)tok * FEAT + cbi * 16);
        float4 f0 = p[0], f1 = p[1], f2 = p[2], f3 = p[3];
        unsigned short* d = xb + (size_t)cbi * TOKS * 16 + tok * 16;
        *reinterpret_cast<bf16x8*>(d)     = pack8(f0, f1);
        *reinterpret_cast<bf16x8*>(d + 8) = pack8(f2, f3);
    } else {
        int i = ((bid - 1024) * 256 + tid) * 8;
        float4 a = *reinterpret_cast<const float4*>(v + i);
        float4 b = *reinterpret_cast<const float4*>(v + i + 4);
        *reinterpret_cast<bf16x8*>(vb + i) = pack8(a, b);
    }
}

// Main: NO LDS, NO barriers. 256 blocks x 8 waves = 2048 independent waves.
// Wave task: one r, 8 token-tiles of 16. B-frags loaded once; A-frags gathered
// straight from L2-resident transposed xb (two contiguous 512B segments/load).
// Block->XCD mapping: xcd = bid&7 owns tokens [xcd*256, +256) -> 1 MB xb slice
// + 2 MB values resident per XCD L2.
__global__ __launch_bounds__(512) void bsp9(const unsigned short* __restrict__ xb,
                                            const unsigned short* __restrict__ vb,
                                            const int* __restrict__ cols,
                                            const float* __restrict__ bias,
                                            float* __restrict__ out) {
    int bid  = blockIdx.x;
    int xcd  = bid & 7;
    int idx  = bid >> 3;                 // 0..31
    int tid  = threadIdx.x;
    int wv   = tid >> 6;                 // 0..7
    int lane = tid & 63;

    int r     = idx * 4 + (wv >> 1);     // each wave owns one r
    int tile0 = xcd * 16 + (wv & 1) * 8; // 8 of the XCD's 16 token-tiles

    int n = lane & 15;        // token-in-tile == output i == D col
    int g = lane >> 4;        // k-quarter
    int h = g & 1;            // 8-elem half within a 16-wide block
    int q = g >> 1;           // which gathered block of the MFMA pair

    // ---- B-fragments + gather offsets: ONCE per wave ----
    bf16x8 bf[16];
    int aoff[16];
    {
        int cb = __builtin_amdgcn_readfirstlane(r) * KB;
        const unsigned short* vbl = vb + ((size_t)r << 13) + (q << 8) + (n << 4) + (h << 3);
        #pragma unroll
        for (int t = 0; t < 16; ++t) {
            bf[t] = *reinterpret_cast<const bf16x8*>(vbl + t * 512);
            int c0 = cols[cb + 2 * t];       // wave-uniform -> s_load
            int c1 = cols[cb + 2 * t + 1];
            int c  = q ? c1 : c0;
            aoff[t] = c * CBW + n * 32 + h * 16;   // byte offset into xb
        }
    }
    float fb = bias[(r << 4) + n];
    const char* xbase = reinterpret_cast<const char*>(xb);

    #pragma unroll 2
    for (int tl = 0; tl < 8; ++tl) {
        int tokbase = (tile0 + tl) << 4;
        int toff    = tokbase << 5;          // *32 bytes per token
        f32x4 a0 = {0.f, 0.f, 0.f, 0.f};
        f32x4 a1 = {0.f, 0.f, 0.f, 0.f};
        #pragma unroll
        for (int t = 0; t < 8; ++t) {
            bf16x8 x0 = *reinterpret_cast<const bf16x8*>(xbase + (aoff[2 * t]     + toff));
            bf16x8 x1 = *reinterpret_cast<const bf16x8*>(xbase + (aoff[2 * t + 1] + toff));
            a0 = __builtin_amdgcn_mfma_f32_16x16x32_bf16(x0, bf[2 * t],     a0, 0, 0, 0);
            a1 = __builtin_amdgcn_mfma_f32_16x16x32_bf16(x1, bf[2 * t + 1], a1, 0, 0, 0);
        }
        int trow = tokbase + (g << 2);
        size_t ob = (size_t)trow * 2048 + (r << 4) + n;
        #pragma unroll
        for (int p = 0; p < 4; ++p)
            out[ob + (size_t)p * 2048] = a0[p] + a1[p] + fb;
    }
}

// ---------------- fallback (small ws): r8 single-dispatch kernel ----------------
__device__ __forceinline__ unsigned pack2_hu(float lo, float hi) {
    unsigned a = __builtin_bit_cast(unsigned, lo) + 0x8000u;
    unsigned b = __builtin_bit_cast(unsigned, hi) + 0x8000u;
    return __builtin_amdgcn_perm(b, a, 0x07060302u);
}
__device__ __forceinline__ bf16x8 pack8_hu(float4 a, float4 b) {
    uint4 u = {pack2_hu(a.x, a.y), pack2_hu(a.z, a.w), pack2_hu(b.x, b.y), pack2_hu(b.z, b.w)};
    return __builtin_bit_cast(bf16x8, u);
}

__global__ __launch_bounds__(512) void bsp_fb(const float* __restrict__ x,
                                              const float* __restrict__ values,
                                              const int* __restrict__ cols,
                                              const float* __restrict__ bias,
                                              float* __restrict__ out) {
    __shared__ __align__(16) unsigned short xs[32 * FEAT];

    int bid  = blockIdx.x;
    int xcd  = bid & 7, slot = bid >> 3;
    int tg   = xcd * 8 + (slot >> 2);
    int rg   = slot & 3;
    int tok0 = tg * 32;
    int r0   = rg * 32;
    int tid  = threadIdx.x;

    {
        int tr = tid >> 8;
        int ch = tid & 255;
        #pragma unroll 4
        for (int it = 0; it < 16; ++it) {
            int t = it * 2 + tr;
            const float4* p = reinterpret_cast<const float4*>(
                x + (size_t)(tok0 + t) * FEAT + ch * 8);
            float4 a = p[0], b = p[1];
            int off = (t << 12) + ((ch << 4) ^ ((t & 7) << 4));
            *reinterpret_cast<bf16x8*>(reinterpret_cast<char*>(xs) + off) = pack8(a, b);
        }
    }
    __syncthreads();

    int wave = tid >> 6;
    int lane = tid & 63;
    int n = lane & 15;
    int g = lane >> 4;
    int h = g & 1;
    int q = g >> 1;
    int mrow = n << 12;
    int axor = (n & 7) << 4;

    #pragma unroll 1
    for (int rr = 0; rr < 4; ++rr) {
        int r = r0 + wave * 4 + rr;
        int cbase = __builtin_amdgcn_readfirstlane(r) * KB;
        bf16x8 bfrag[16];
        int aaddr[16];
        const float* vfl = values + ((size_t)r << 13) + (q << 8) + (n << 4) + (h << 3);
        #pragma unroll
        for (int t = 0; t < 16; ++t) {
            const float4* pv = reinterpret_cast<const float4*>(vfl + t * 512);
            bfrag[t] = pack8_hu(pv[0], pv[1]);
            int c0 = cols[cbase + 2 * t];
            int c1 = cols[cbase + 2 * t + 1];
            int c  = q ? c1 : c0;
            aaddr[t] = mrow + (((c << 5) + (h << 4)) ^ axor);
        }
        float fb = bias[(r << 4) + n];
        #pragma unroll
        for (int sx = 0; sx < 2; ++sx) {
            const char* xbp = reinterpret_cast<const char*>(xs) + (sx << 16);
            f32x4 acc0 = {0.f, 0.f, 0.f, 0.f};
            f32x4 acc1 = {0.f, 0.f, 0.f, 0.f};
            #pragma unroll
            for (int t = 0; t < 8; ++t) {
                bf16x8 a0 = *reinterpret_cast<const bf16x8*>(xbp + aaddr[2 * t]);
                bf16x8 a1 = *reinterpret_cast<const bf16x8*>(xbp + aaddr[2 * t + 1]);
                acc0 = __builtin_amdgcn_mfma_f32_16x16x32_bf16(a0, bfrag[2 * t],     acc0, 0, 0, 0);
                acc1 = __builtin_amdgcn_mfma_f32_16x16x32_bf16(a1, bfrag[2 * t + 1], acc1, 0, 0, 0);
            }
            int trow = tok0 + (sx << 4) + (g << 2);
            size_t ob = (size_t)trow * 2048 + (r << 4) + n;
            #pragma unroll
            for (int p = 0; p < 4; ++p)
                out[ob + (size_t)p * 2048] = acc0[p] + acc1[p] + fb;
        }
    }
}

extern "C" void kernel_launch(void* const* d_in, const int* in_sizes, int n_in,
                              void* d_out, int out_size, void* d_ws, size_t ws_size,
                              hipStream_t stream) {
    const float* x      = (const float*)d_in[0];
    const float* values = (const float*)d_in[1];
    const int*   cols   = (const int*)d_in[2];
    const float* bias   = (const float*)d_in[3];
    float*       out    = (float*)d_out;

    const size_t xb_bytes = (size_t)NCB * TOKS * 16 * 2;   // 8 MiB
    const size_t vb_bytes = (size_t)NR * KB * 256 * 2;     // 2 MiB

    if (ws_size >= xb_bytes + vb_bytes) {
        unsigned short* xbuf = (unsigned short*)d_ws;
        unsigned short* vbuf = (unsigned short*)((char*)d_ws + xb_bytes);
        prep9<<<1024 + 512, 256, 0, stream>>>(x, values, xbuf, vbuf);
        bsp9<<<256, 512, 0, stream>>>(xbuf, vbuf, cols, bias, out);
    } else {
        bsp_fb<<<256, 512, 0, stream>>>(x, values, cols, bias, out);
    }
}